// Round 8
// baseline (626.807 us; speedup 1.0000x reference)
//
#include <hip/hip_runtime.h>
#include <math.h>

#define BATCH 8
#define CCH   256
#define HH    64
#define WW    64
#define NN    4096                    // HH*WW

#define BNC   (BATCH * NN * CCH)      // 8,388,608 elems per tensor
#define WELEMS (3 * 8 * 9 * 256 * 32) // 1,769,472 fp16 weight elems per hi/lo

typedef __bf16   bf16x8 __attribute__((ext_vector_type(8)));
typedef _Float16 f16x8  __attribute__((ext_vector_type(8)));
typedef _Float16 f16x4  __attribute__((ext_vector_type(4)));
typedef float    f32x4  __attribute__((ext_vector_type(4)));

// ---------------------------------------------------------------------------
// Weights: OIHW fp32 -> fp16 hi/lo, layout [conv][cc8][tap9][co256][ci32]
// ---------------------------------------------------------------------------
__global__ void wtrans_kernel(const float* __restrict__ w1,
                              const float* __restrict__ w2,
                              const float* __restrict__ w3,
                              _Float16* __restrict__ Whi,
                              _Float16* __restrict__ Wlo) {
    int e = blockIdx.x * 256 + threadIdx.x;      // 0 .. WELEMS-1
    int t = e;
    const int ci  = t & 31;  t >>= 5;
    const int co  = t & 255; t >>= 8;
    const int tap = t % 9;   t /= 9;
    const int cc  = t & 7;   t >>= 3;
    const int conv = t;
    const float* src = (conv == 0) ? w1 : (conv == 1) ? w2 : w3;
    const float v = src[co * 2304 + (cc * 32 + ci) * 9 + tap];
    const _Float16 h = (_Float16)v;
    Whi[e] = h;
    Wlo[e] = (_Float16)(v - (float)h);
}

// ---------------------------------------------------------------------------
// X: [b][ci][h][w] fp32 -> Xhi/Xlo fp16 [b][h][w][ci]  (transpose via LDS)
// ---------------------------------------------------------------------------
__global__ __launch_bounds__(256)
void xsplit_kernel(const float* __restrict__ X,
                   _Float16* __restrict__ Xhi, _Float16* __restrict__ Xlo) {
    __shared__ float T[64][65];
    const int h = blockIdx.x, c0 = blockIdx.y * 64, bb = blockIdx.z;
    const int t = threadIdx.x;
    const int row = t >> 2, q = (t & 3) * 16;
#pragma unroll
    for (int k = 0; k < 4; ++k) {
        float4 v = *(const float4*)&X[(((size_t)bb * CCH + c0 + row) * HH + h) * WW + q + k * 4];
        *(float4*)&T[row][q + k * 4] = v;
    }
    __syncthreads();
    f16x8 h0, h1, l0, l1;
#pragma unroll
    for (int j = 0; j < 8; ++j) {
        float v = T[q + j][row];
        _Float16 hh = (_Float16)v;
        h0[j] = hh; l0[j] = (_Float16)(v - (float)hh);
    }
#pragma unroll
    for (int j = 0; j < 8; ++j) {
        float v = T[q + 8 + j][row];
        _Float16 hh = (_Float16)v;
        h1[j] = hh; l1[j] = (_Float16)(v - (float)hh);
    }
    const size_t g = (((size_t)bb * HH + h) * WW + row) * CCH + c0 + q;
    *(f16x8*)(Xhi + g) = h0;  *(f16x8*)(Xhi + g + 8) = h1;
    *(f16x8*)(Xlo + g) = l0;  *(f16x8*)(Xlo + g + 8) = l1;
}

// ---------------------------------------------------------------------------
// MFMA implicit-GEMM conv 3x3 SAME + bias, v6 (unchanged from round 6).
// ---------------------------------------------------------------------------
__global__ __launch_bounds__(512, 2)
void conv_mfma_kernel(const _Float16* __restrict__ Xhi, const _Float16* __restrict__ Xlo,
                      const _Float16* __restrict__ Whi, const _Float16* __restrict__ Wlo,
                      const float* __restrict__ b1, const float* __restrict__ b2,
                      const float* __restrict__ b3,
                      __bf16* __restrict__ Qhi, __bf16* __restrict__ Qlo,
                      __bf16* __restrict__ Khi, __bf16* __restrict__ Klo,
                      float* __restrict__ Dws) {
    const int h0   = blockIdx.x * 2;
    const int bb   = blockIdx.y;
    const int conv = blockIdx.z;
    const int tid  = threadIdx.x;
    const int wave = tid >> 6;
    const int lane = tid & 63;
    const int quad = lane >> 4;
    const int l16  = lane & 15;
    const int mg   = wave >> 2;
    const int ng   = wave & 3;

    // [4 rows][66 cols][32 ch], col 0 and 65 are zero pads
    __shared__ _Float16 XsH[4 * 66 * 32];
    __shared__ _Float16 XsL[4 * 66 * 32];

    const bool threePass = (conv < 2);
    const float* bias = (conv == 0) ? b1 : (conv == 1) ? b2 : b3;

    f32x4 acc[4][4];
#pragma unroll
    for (int j = 0; j < 4; ++j) {
        const float bv = bias[ng * 64 + j * 16 + l16];
#pragma unroll
        for (int i = 0; i < 4; ++i) acc[i][j] = (f32x4){bv, bv, bv, bv};
    }

    const f16x8 zf = {0, 0, 0, 0, 0, 0, 0, 0};
    const int xrow = tid >> 7;
    const int xw   = (tid >> 1) & 63;
    const int xch  = (tid & 1) * 16;
    const int xc0  = (tid & 1) * 2;       // first 16B-chunk index (0 or 2)

    // zero the pad columns once (cols 0 and 65, all 4 rows, all 32 ch)
    if (tid < 256) {
        const int zr = tid >> 6, zc = ((tid >> 5) & 1) ? 65 : 0, zch = tid & 31;
        XsH[(zr * 66 + zc) * 32 + zch] = (_Float16)0;
        XsL[(zr * 66 + zc) * 32 + zch] = (_Float16)0;
    }

    // per-lane LDS read bases for dw = 0,1,2 (col = i*16 + l16 + dw)
    int xb[3];
#pragma unroll
    for (int dw = 0; dw < 3; ++dw)
        xb[dw] = mg * 2112 + (l16 + dw) * 32 + ((quad ^ ((l16 + dw) & 3)) * 8);

    // W direct-from-global: per-lane offset inside a tap block [co256][ci32]
    const int wloff = (ng * 64 + l16) * 32 + quad * 8;
    const _Float16* WhB = Whi + (size_t)conv * 589824;
    const _Float16* WlB = Wlo + (size_t)conv * 589824;

    // W tap double-buffers: wbh/wbl[parity][j]
    f16x8 wbh[2][4], wbl[2][4];
#pragma unroll
    for (int j = 0; j < 4; ++j) {
        wbh[0][j] = *(const f16x8*)(WhB + wloff + j * 512);
        wbl[0][j] = zf;
        if (threePass) wbl[0][j] = *(const f16x8*)(WlB + wloff + j * 512);
    }

    for (int cc2 = 0; cc2 < 4; ++cc2) {
#pragma unroll
        for (int ccp = 0; ccp < 2; ++ccp) {
            const int cc = cc2 * 2 + ccp;
            __syncthreads();                  // previous cc's LDS reads done
            {
                const int h = h0 - 1 + xrow;
                f16x8 a0 = zf, a1 = zf, b0 = zf, b1v = zf;
                if ((unsigned)h < (unsigned)HH) {
                    const size_t g = (((size_t)bb * HH + h) * WW + xw) * CCH + cc * 32 + xch;
                    a0 = *(const f16x8*)(Xhi + g);  a1 = *(const f16x8*)(Xhi + g + 8);
                    if (threePass) { b0 = *(const f16x8*)(Xlo + g);  b1v = *(const f16x8*)(Xlo + g + 8); }
                }
                // write col xw+1 (data cols are 1..64), swizzle units by (col&3)
                const int col = xw + 1;
                const int lbase = (xrow * 66 + col) * 32;
                const int s3 = col & 3;
                *(f16x8*)&XsH[lbase + ((xc0 ^ s3) * 8)]       = a0;
                *(f16x8*)&XsH[lbase + (((xc0 + 1) ^ s3) * 8)] = a1;
                if (threePass) {
                    *(f16x8*)&XsL[lbase + ((xc0 ^ s3) * 8)]       = b0;
                    *(f16x8*)&XsL[lbase + (((xc0 + 1) ^ s3) * 8)] = b1v;
                }
            }
            __syncthreads();                  // X tile visible

#pragma unroll
            for (int tap = 0; tap < 9; ++tap) {
                const int p  = (ccp + tap) & 1;   // compile-time parity
                const int np = p ^ 1;
                // ---- prefetch next tap's W fragments into ping buffer ----
                {
                    const int nst = cc * 9 + tap + 1;          // 1..72
                    const size_t nb = (size_t)(nst == 72 ? 0 : nst) * 8192 + wloff;
#pragma unroll
                    for (int j = 0; j < 4; ++j) {
                        wbh[np][j] = *(const f16x8*)(WhB + nb + j * 512);
                        if (threePass) wbl[np][j] = *(const f16x8*)(WlB + nb + j * 512);
                    }
                }
                // ---- LDS A fragments ----
                const int dh = tap / 3, dw = tap % 3;          // compile-time
                f16x8 ah[4], al[4];
#pragma unroll
                for (int i = 0; i < 4; ++i) {
                    const int off = xb[dw] + dh * 2112 + i * 512;  // imm-folded
                    ah[i] = *(const f16x8*)&XsH[off];
                    if (threePass) al[i] = *(const f16x8*)&XsL[off];
                }
                // ---- MFMA with pong buffer (filled one full tap ago) ----
#pragma unroll
                for (int j = 0; j < 4; ++j) {
                    if (threePass) {
#pragma unroll
                        for (int i = 0; i < 4; ++i) {
                            acc[i][j] = __builtin_amdgcn_mfma_f32_16x16x32_f16(ah[i], wbh[p][j], acc[i][j], 0, 0, 0);
                            acc[i][j] = __builtin_amdgcn_mfma_f32_16x16x32_f16(al[i], wbh[p][j], acc[i][j], 0, 0, 0);
                            acc[i][j] = __builtin_amdgcn_mfma_f32_16x16x32_f16(ah[i], wbl[p][j], acc[i][j], 0, 0, 0);
                        }
                    } else {
#pragma unroll
                        for (int i = 0; i < 4; ++i)
                            acc[i][j] = __builtin_amdgcn_mfma_f32_16x16x32_f16(ah[i], wbh[p][j], acc[i][j], 0, 0, 0);
                    }
                }
            }
        }
    }

    const size_t nb = (size_t)bb * NN + (size_t)(h0 + mg) * 64;
    if (threePass) {
        __bf16* Hi = conv ? Khi : Qhi;
        __bf16* Lo = conv ? Klo : Qlo;
#pragma unroll
        for (int i = 0; i < 4; ++i) {
            const int wx0 = i * 16 + quad * 4;
#pragma unroll
            for (int j = 0; j < 4; ++j) {
                const int co = ng * 64 + j * 16 + l16;
#pragma unroll
                for (int r = 0; r < 4; ++r) {
                    const float v = acc[i][j][r];
                    const size_t idx = (nb + wx0 + r) * CCH + co;
                    const __bf16 hq = (__bf16)v;
                    Hi[idx] = hq;
                    Lo[idx] = (__bf16)(v - (float)hq);
                }
            }
        }
    } else {
#pragma unroll
        for (int i = 0; i < 4; ++i) {
            const int wx0 = i * 16 + quad * 4;
#pragma unroll
            for (int j = 0; j < 4; ++j) {
                const int co = ng * 64 + j * 16 + l16;
#pragma unroll
                for (int r = 0; r < 4; ++r)
                    Dws[(nb + wx0 + r) * CCH + co] = acc[i][j][r];
            }
        }
    }
}

// ---------------------------------------------------------------------------
// Transpose D (fp32 [b][n][c]) -> Vt (fp16 [b][c][n]).
// ---------------------------------------------------------------------------
__global__ __launch_bounds__(256)
void transpose_v_kernel(const float* __restrict__ D, _Float16* __restrict__ Vt) {
    __shared__ float T[64][65];
    const int n0 = blockIdx.x * 64, c0 = blockIdx.y * 64, bb = blockIdx.z;
    const int t = threadIdx.x;
    const int row = t >> 2, q = (t & 3) * 16;
#pragma unroll
    for (int k = 0; k < 4; ++k) {
        float4 v = *(const float4*)(D + ((size_t)bb * NN + n0 + row) * CCH + c0 + q + k * 4);
        *(float4*)&T[row][q + k * 4] = v;
    }
    __syncthreads();
    f16x8 o0, o1;
#pragma unroll
    for (int j = 0; j < 8; ++j) o0[j] = (_Float16)T[q + j][row];
#pragma unroll
    for (int j = 0; j < 8; ++j) o1[j] = (_Float16)T[q + 8 + j][row];
    _Float16* dst = Vt + ((size_t)bb * CCH + c0 + row) * NN + n0 + q;
    *(f16x8*)dst = o0;
    *(f16x8*)(dst + 8) = o1;
}

// ---------------------------------------------------------------------------
// MFMA flash attention v8: attn is LDS-throughput-bound (~79% LDS-unit busy)
// with the residual gap = barrier-lockstep idle (all waves in one block sync
// through softmax together, LDS idles).  v8 splits the work into TWO
// INDEPENDENT blocks per CU: 256 threads / 4 waves / 64 q per block, grid
// 512, single K chunk buffer (2 barriers per chunk), LDS 50688 B -> 2
// blocks/CU.  Same waves/CU, same LDS volume, same MFMA; the two blocks'
// phases interleave so one block's S-phase ds_reads fill the other's
// softmax/barrier bubbles.  PV channel-ownership: wave owns 64 channels
// (cf 0..3); pf held [4][4]; V per-cf direct from L2.
// batch = blockIdx&7 pins batch -> XCD.
// ---------------------------------------------------------------------------
__global__ __launch_bounds__(256, 2)
void attn_mfma_kernel(const __bf16* __restrict__ Qhi, const __bf16* __restrict__ Qlo,
                      const __bf16* __restrict__ Khi, const __bf16* __restrict__ Klo,
                      const _Float16* __restrict__ Vt, const float* __restrict__ alpha_p,
                      float* __restrict__ out) {
    const int bb = blockIdx.x & 7;     // batch -> XCD
    const int qb = blockIdx.x >> 3;    // 0..63
    const int n0 = qb * 64;
    const int tid  = threadIdx.x;      // 0..255
    const int wave = tid >> 6;         // 0..3
    const int lane = tid & 63;
    const int quad = lane >> 4;
    const int l16  = lane & 15;
    const int xq   = l16 & 7;

    extern __shared__ __align__(16) unsigned char smem[];
    __bf16*   KsHi = (__bf16*)(smem);             // [128][64] swizzled, 16KB
    __bf16*   KsLo = (__bf16*)(smem + 16384);     // [128][64] swizzled, 16KB
    _Float16* PwA  = (_Float16*)(smem + 32768);   // 4 waves x [16][136] fp16
    float*    Ssc  = (float*)(smem + 50176);      // per-q rescale factor [64]
    float*    Linv = (float*)(smem + 50432);      // per-q alpha/l at end [64]
    _Float16* Pw   = PwA + wave * (16 * 136);

    // Q resident in registers as B-frags: this wave's 16 q-rows
    bf16x8 qh[8], ql[8];
    {
        const size_t base = ((size_t)bb * NN + n0 + wave * 16 + l16) * CCH + quad * 8;
#pragma unroll
        for (int ks = 0; ks < 8; ++ks) {
            qh[ks] = *(const bf16x8*)(Qhi + base + ks * 32);
            ql[ks] = *(const bf16x8*)(Qlo + base + ks * 32);
        }
    }

    // O^T accumulators, channel-ownership: c = wave*64 + cf*16 + quad*4 + r,
    // q = n0 + qt*16 + l16
    f32x4 Oacc[4][4];
#pragma unroll
    for (int cf = 0; cf < 4; ++cf)
#pragma unroll
        for (int qt = 0; qt < 4; ++qt) Oacc[cf][qt] = (f32x4){0.f, 0.f, 0.f, 0.f};
    float m_i = -INFINITY, l_i = 0.f;

    // K staging coords: 2 thr/row (128 rows), 4x16B units each per hi/lo
    const int krow = tid >> 1, kh2 = tid & 1;

    bf16x8 kph[4], kpl[4];     // K-chunk prefetch regs

    auto kload = [&](int m0_, int cc_) {
#pragma unroll
        for (int i = 0; i < 4; ++i) {
            const int u = kh2 * 4 + i;
            const size_t g = ((size_t)bb * NN + m0_ + krow) * CCH + cc_ * 64 + u * 8;
            kph[i] = *(const bf16x8*)(Khi + g);
            kpl[i] = *(const bf16x8*)(Klo + g);
        }
    };
    auto kwrite = [&]() {
#pragma unroll
        for (int i = 0; i < 4; ++i) {
            const int u = kh2 * 4 + i;
            const int lo = krow * 64 + ((u ^ (krow & 7)) * 8);
            *(bf16x8*)&KsHi[lo] = kph[i];
            *(bf16x8*)&KsLo[lo] = kpl[i];
        }
    };

    f32x4 Sacc[8];
    auto schunk = [&](int cc) {
#pragma unroll
        for (int ks = 0; ks < 2; ++ks) {
            const int kq = cc * 2 + ks;
#pragma unroll
            for (int kvt = 0; kvt < 8; ++kvt) {
                const int off = (kvt * 16 + l16) * 64 + (((ks * 4 + quad) ^ xq) * 8);
                const bf16x8 kh = *(const bf16x8*)&KsHi[off];
                const bf16x8 kl = *(const bf16x8*)&KsLo[off];
                Sacc[kvt] = __builtin_amdgcn_mfma_f32_16x16x32_bf16(kh, qh[kq], Sacc[kvt], 0, 0, 0);
                Sacc[kvt] = __builtin_amdgcn_mfma_f32_16x16x32_bf16(kl, qh[kq], Sacc[kvt], 0, 0, 0);
                Sacc[kvt] = __builtin_amdgcn_mfma_f32_16x16x32_bf16(kh, ql[kq], Sacc[kvt], 0, 0, 0);
            }
        }
    };

    // prologue: stage K chunk0 of tile 0
    kload(0, 0);
    kwrite();
    __syncthreads();

    for (int t = 0; t < 32; ++t) {
        const int m0 = t * 128;
#pragma unroll
        for (int kvt = 0; kvt < 8; ++kvt) Sacc[kvt] = (f32x4){0.f, 0.f, 0.f, 0.f};

        // ---- S chunks 0..3, single buffer, reg-prefetch pipelining ----
#pragma unroll
        for (int cc = 0; cc < 4; ++cc) {
            // prefetch next chunk (cc==3: chunk0 of next tile) into regs
            kload(cc < 3 ? m0 : ((t == 31) ? 0 : m0 + 128), (cc + 1) & 3);
            schunk(cc);                // consume current buffer
            __syncthreads();           // all waves done reading buffer
            kwrite();                  // overwrite with next chunk
            __syncthreads();           // next chunk visible
        }

        // ---- online softmax over 128 kv (this wave's 16 q-rows) ----
        float mx = -INFINITY;
#pragma unroll
        for (int kvt = 0; kvt < 8; ++kvt)
#pragma unroll
            for (int r = 0; r < 4; ++r) mx = fmaxf(mx, Sacc[kvt][r]);
        mx = fmaxf(mx, __shfl_xor(mx, 16, 64));
        mx = fmaxf(mx, __shfl_xor(mx, 32, 64));
        const float mnew = fmaxf(m_i, mx);
        float rs = 0.f;
#pragma unroll
        for (int kvt = 0; kvt < 8; ++kvt) {
            f16x4 pw;
#pragma unroll
            for (int r = 0; r < 4; ++r) {
                const float p = __expf(Sacc[kvt][r] - mnew);
                rs += p;
                pw[r] = (_Float16)p;
            }
            *(f16x4*)&Pw[l16 * 136 + kvt * 16 + quad * 4] = pw;
        }
        rs += __shfl_xor(rs, 16, 64);
        rs += __shfl_xor(rs, 32, 64);
        const float scale = __expf(m_i - mnew);    // 0 on first tile
        if (quad == 0) Ssc[wave * 16 + l16] = scale;
        l_i = l_i * scale + rs;
        m_i = mnew;
        __syncthreads();               // Pw + Ssc visible to all waves

        // ---- rescale O by per-q factors (broadcast reads) ----
        float sc[4];
#pragma unroll
        for (int qt = 0; qt < 4; ++qt) sc[qt] = Ssc[qt * 16 + l16];
#pragma unroll
        for (int cf = 0; cf < 4; ++cf)
#pragma unroll
            for (int qt = 0; qt < 4; ++qt) {
                Oacc[cf][qt][0] *= sc[qt];
                Oacc[cf][qt][1] *= sc[qt];
                Oacc[cf][qt][2] *= sc[qt];
                Oacc[cf][qt][3] *= sc[qt];
            }

        // ---- O^T += V^T P^T over all 64 q (channel-ownership) ----
        f16x8 pf[4][4];
#pragma unroll
        for (int qt = 0; qt < 4; ++qt)
#pragma unroll
            for (int kvf = 0; kvf < 4; ++kvf)
                pf[qt][kvf] = *(const f16x8*)&PwA[qt * 2176 + l16 * 136 + kvf * 32 + quad * 8];
#pragma unroll
        for (int cf = 0; cf < 4; ++cf) {
            f16x8 vfc[4];
#pragma unroll
            for (int kvf = 0; kvf < 4; ++kvf)
                vfc[kvf] = *(const f16x8*)(Vt +
                    ((size_t)bb * CCH + wave * 64 + cf * 16 + l16) * NN +
                    m0 + kvf * 32 + quad * 8);
#pragma unroll
            for (int qt = 0; qt < 4; ++qt)
#pragma unroll
                for (int kvf = 0; kvf < 4; ++kvf)
                    Oacc[cf][qt] = __builtin_amdgcn_mfma_f32_16x16x32_f16(vfc[kvf], pf[qt][kvf], Oacc[cf][qt], 0, 0, 0);
        }
        __syncthreads();               // Pw reads done before next softmax
    }

    // ---- epilogue: per-q 1/l broadcast, *alpha, write out[b][c][n] ----
    const float alpha = *alpha_p;
    if (quad == 0) Linv[wave * 16 + l16] = alpha / l_i;
    __syncthreads();
#pragma unroll
    for (int qt = 0; qt < 4; ++qt) {
        const float inv = Linv[qt * 16 + l16];
#pragma unroll
        for (int cf = 0; cf < 4; ++cf)
#pragma unroll
            for (int r = 0; r < 4; ++r) {
                const int c = wave * 64 + cf * 16 + quad * 4 + r;
                out[((size_t)bb * CCH + c) * NN + n0 + qt * 16 + l16] = Oacc[cf][qt][r] * inv;
            }
    }
}

// ---------------------------------------------------------------------------
extern "C" void kernel_launch(void* const* d_in, const int* in_sizes, int n_in,
                              void* d_out, int out_size, void* d_ws, size_t ws_size,
                              hipStream_t stream) {
    const float* X  = (const float*)d_in[0];
    const float* w1 = (const float*)d_in[1];
    const float* b1 = (const float*)d_in[2];
    const float* w2 = (const float*)d_in[3];
    const float* b2 = (const float*)d_in[4];
    const float* w3 = (const float*)d_in[5];
    const float* b3 = (const float*)d_in[6];
    const float* alpha = (const float*)d_in[7];
    float* out = (float*)d_out;

    float*    Dws = (float*)d_ws;
    __bf16*   Qhi = (__bf16*)(Dws + (size_t)BNC);
    __bf16*   Qlo = Qhi + (size_t)BNC;
    __bf16*   Khi = Qlo + (size_t)BNC;
    __bf16*   Klo = Khi + (size_t)BNC;
    _Float16* Vt  = (_Float16*)(Klo + (size_t)BNC);
    _Float16* Xhi = Vt + (size_t)BNC;
    _Float16* Xlo = Xhi + (size_t)BNC;
    _Float16* Whi = Xlo + (size_t)BNC;
    _Float16* Wlo = Whi + (size_t)WELEMS;

    wtrans_kernel<<<dim3(WELEMS / 256), 256, 0, stream>>>(w1, w2, w3, Whi, Wlo);

    xsplit_kernel<<<dim3(HH, CCH / 64, BATCH), 256, 0, stream>>>(X, Xhi, Xlo);

    conv_mfma_kernel<<<dim3(HH / 2, BATCH, 3), 512, 0, stream>>>(
        Xhi, Xlo, Whi, Wlo, b1, b2, b3, Qhi, Qlo, Khi, Klo, Dws);

    transpose_v_kernel<<<dim3(NN / 64, CCH / 64, BATCH), 256, 0, stream>>>(Dws, Vt);

    // dynamic LDS: K 32KB + P 17KB + Ssc/Linv 0.5KB = 50688 B -> 2 blocks/CU
    attn_mfma_kernel<<<dim3(512), 256, 50688, stream>>>(
        Qhi, Qlo, Khi, Klo, Vt, alpha, out);
}

// Round 9
// 559.565 us; speedup vs baseline: 1.1202x; 1.1202x over previous
//
#include <hip/hip_runtime.h>
#include <math.h>

#define BATCH 8
#define CCH   256
#define HH    64
#define WW    64
#define NN    4096                    // HH*WW

#define BNC   (BATCH * NN * CCH)      // 8,388,608 elems per tensor
#define WELEMS (3 * 8 * 9 * 256 * 32) // 1,769,472 fp16 weight elems per hi/lo

typedef __bf16   bf16x8 __attribute__((ext_vector_type(8)));
typedef _Float16 f16x8  __attribute__((ext_vector_type(8)));
typedef _Float16 f16x4  __attribute__((ext_vector_type(4)));
typedef float    f32x4  __attribute__((ext_vector_type(4)));

// ---------------------------------------------------------------------------
// Weights: OIHW fp32 -> fp16 hi/lo, layout [conv][cc8][tap9][co256][ci32]
// ---------------------------------------------------------------------------
__global__ void wtrans_kernel(const float* __restrict__ w1,
                              const float* __restrict__ w2,
                              const float* __restrict__ w3,
                              _Float16* __restrict__ Whi,
                              _Float16* __restrict__ Wlo) {
    int e = blockIdx.x * 256 + threadIdx.x;      // 0 .. WELEMS-1
    int t = e;
    const int ci  = t & 31;  t >>= 5;
    const int co  = t & 255; t >>= 8;
    const int tap = t % 9;   t /= 9;
    const int cc  = t & 7;   t >>= 3;
    const int conv = t;
    const float* src = (conv == 0) ? w1 : (conv == 1) ? w2 : w3;
    const float v = src[co * 2304 + (cc * 32 + ci) * 9 + tap];
    const _Float16 h = (_Float16)v;
    Whi[e] = h;
    Wlo[e] = (_Float16)(v - (float)h);
}

// ---------------------------------------------------------------------------
// X: [b][ci][h][w] fp32 -> Xhi/Xlo fp16 [b][h][w][ci]  (transpose via LDS)
// ---------------------------------------------------------------------------
__global__ __launch_bounds__(256)
void xsplit_kernel(const float* __restrict__ X,
                   _Float16* __restrict__ Xhi, _Float16* __restrict__ Xlo) {
    __shared__ float T[64][65];
    const int h = blockIdx.x, c0 = blockIdx.y * 64, bb = blockIdx.z;
    const int t = threadIdx.x;
    const int row = t >> 2, q = (t & 3) * 16;
#pragma unroll
    for (int k = 0; k < 4; ++k) {
        float4 v = *(const float4*)&X[(((size_t)bb * CCH + c0 + row) * HH + h) * WW + q + k * 4];
        *(float4*)&T[row][q + k * 4] = v;
    }
    __syncthreads();
    f16x8 h0, h1, l0, l1;
#pragma unroll
    for (int j = 0; j < 8; ++j) {
        float v = T[q + j][row];
        _Float16 hh = (_Float16)v;
        h0[j] = hh; l0[j] = (_Float16)(v - (float)hh);
    }
#pragma unroll
    for (int j = 0; j < 8; ++j) {
        float v = T[q + 8 + j][row];
        _Float16 hh = (_Float16)v;
        h1[j] = hh; l1[j] = (_Float16)(v - (float)hh);
    }
    const size_t g = (((size_t)bb * HH + h) * WW + row) * CCH + c0 + q;
    *(f16x8*)(Xhi + g) = h0;  *(f16x8*)(Xhi + g + 8) = h1;
    *(f16x8*)(Xlo + g) = l0;  *(f16x8*)(Xlo + g + 8) = l1;
}

// ---------------------------------------------------------------------------
// MFMA implicit-GEMM conv 3x3 SAME + bias, v6 (unchanged from round 6).
// ---------------------------------------------------------------------------
__global__ __launch_bounds__(512, 2)
void conv_mfma_kernel(const _Float16* __restrict__ Xhi, const _Float16* __restrict__ Xlo,
                      const _Float16* __restrict__ Whi, const _Float16* __restrict__ Wlo,
                      const float* __restrict__ b1, const float* __restrict__ b2,
                      const float* __restrict__ b3,
                      __bf16* __restrict__ Qhi, __bf16* __restrict__ Qlo,
                      __bf16* __restrict__ Khi, __bf16* __restrict__ Klo,
                      float* __restrict__ Dws) {
    const int h0   = blockIdx.x * 2;
    const int bb   = blockIdx.y;
    const int conv = blockIdx.z;
    const int tid  = threadIdx.x;
    const int wave = tid >> 6;
    const int lane = tid & 63;
    const int quad = lane >> 4;
    const int l16  = lane & 15;
    const int mg   = wave >> 2;
    const int ng   = wave & 3;

    // [4 rows][66 cols][32 ch], col 0 and 65 are zero pads
    __shared__ _Float16 XsH[4 * 66 * 32];
    __shared__ _Float16 XsL[4 * 66 * 32];

    const bool threePass = (conv < 2);
    const float* bias = (conv == 0) ? b1 : (conv == 1) ? b2 : b3;

    f32x4 acc[4][4];
#pragma unroll
    for (int j = 0; j < 4; ++j) {
        const float bv = bias[ng * 64 + j * 16 + l16];
#pragma unroll
        for (int i = 0; i < 4; ++i) acc[i][j] = (f32x4){bv, bv, bv, bv};
    }

    const f16x8 zf = {0, 0, 0, 0, 0, 0, 0, 0};
    const int xrow = tid >> 7;
    const int xw   = (tid >> 1) & 63;
    const int xch  = (tid & 1) * 16;
    const int xc0  = (tid & 1) * 2;       // first 16B-chunk index (0 or 2)

    // zero the pad columns once (cols 0 and 65, all 4 rows, all 32 ch)
    if (tid < 256) {
        const int zr = tid >> 6, zc = ((tid >> 5) & 1) ? 65 : 0, zch = tid & 31;
        XsH[(zr * 66 + zc) * 32 + zch] = (_Float16)0;
        XsL[(zr * 66 + zc) * 32 + zch] = (_Float16)0;
    }

    // per-lane LDS read bases for dw = 0,1,2 (col = i*16 + l16 + dw)
    int xb[3];
#pragma unroll
    for (int dw = 0; dw < 3; ++dw)
        xb[dw] = mg * 2112 + (l16 + dw) * 32 + ((quad ^ ((l16 + dw) & 3)) * 8);

    // W direct-from-global: per-lane offset inside a tap block [co256][ci32]
    const int wloff = (ng * 64 + l16) * 32 + quad * 8;
    const _Float16* WhB = Whi + (size_t)conv * 589824;
    const _Float16* WlB = Wlo + (size_t)conv * 589824;

    // W tap double-buffers: wbh/wbl[parity][j]
    f16x8 wbh[2][4], wbl[2][4];
#pragma unroll
    for (int j = 0; j < 4; ++j) {
        wbh[0][j] = *(const f16x8*)(WhB + wloff + j * 512);
        wbl[0][j] = zf;
        if (threePass) wbl[0][j] = *(const f16x8*)(WlB + wloff + j * 512);
    }

    for (int cc2 = 0; cc2 < 4; ++cc2) {
#pragma unroll
        for (int ccp = 0; ccp < 2; ++ccp) {
            const int cc = cc2 * 2 + ccp;
            __syncthreads();                  // previous cc's LDS reads done
            {
                const int h = h0 - 1 + xrow;
                f16x8 a0 = zf, a1 = zf, b0 = zf, b1v = zf;
                if ((unsigned)h < (unsigned)HH) {
                    const size_t g = (((size_t)bb * HH + h) * WW + xw) * CCH + cc * 32 + xch;
                    a0 = *(const f16x8*)(Xhi + g);  a1 = *(const f16x8*)(Xhi + g + 8);
                    if (threePass) { b0 = *(const f16x8*)(Xlo + g);  b1v = *(const f16x8*)(Xlo + g + 8); }
                }
                // write col xw+1 (data cols are 1..64), swizzle units by (col&3)
                const int col = xw + 1;
                const int lbase = (xrow * 66 + col) * 32;
                const int s3 = col & 3;
                *(f16x8*)&XsH[lbase + ((xc0 ^ s3) * 8)]       = a0;
                *(f16x8*)&XsH[lbase + (((xc0 + 1) ^ s3) * 8)] = a1;
                if (threePass) {
                    *(f16x8*)&XsL[lbase + ((xc0 ^ s3) * 8)]       = b0;
                    *(f16x8*)&XsL[lbase + (((xc0 + 1) ^ s3) * 8)] = b1v;
                }
            }
            __syncthreads();                  // X tile visible

#pragma unroll
            for (int tap = 0; tap < 9; ++tap) {
                const int p  = (ccp + tap) & 1;   // compile-time parity
                const int np = p ^ 1;
                // ---- prefetch next tap's W fragments into ping buffer ----
                {
                    const int nst = cc * 9 + tap + 1;          // 1..72
                    const size_t nb = (size_t)(nst == 72 ? 0 : nst) * 8192 + wloff;
#pragma unroll
                    for (int j = 0; j < 4; ++j) {
                        wbh[np][j] = *(const f16x8*)(WhB + nb + j * 512);
                        if (threePass) wbl[np][j] = *(const f16x8*)(WlB + nb + j * 512);
                    }
                }
                // ---- LDS A fragments ----
                const int dh = tap / 3, dw = tap % 3;          // compile-time
                f16x8 ah[4], al[4];
#pragma unroll
                for (int i = 0; i < 4; ++i) {
                    const int off = xb[dw] + dh * 2112 + i * 512;  // imm-folded
                    ah[i] = *(const f16x8*)&XsH[off];
                    if (threePass) al[i] = *(const f16x8*)&XsL[off];
                }
                // ---- MFMA with pong buffer (filled one full tap ago) ----
#pragma unroll
                for (int j = 0; j < 4; ++j) {
                    if (threePass) {
#pragma unroll
                        for (int i = 0; i < 4; ++i) {
                            acc[i][j] = __builtin_amdgcn_mfma_f32_16x16x32_f16(ah[i], wbh[p][j], acc[i][j], 0, 0, 0);
                            acc[i][j] = __builtin_amdgcn_mfma_f32_16x16x32_f16(al[i], wbh[p][j], acc[i][j], 0, 0, 0);
                            acc[i][j] = __builtin_amdgcn_mfma_f32_16x16x32_f16(ah[i], wbl[p][j], acc[i][j], 0, 0, 0);
                        }
                    } else {
#pragma unroll
                        for (int i = 0; i < 4; ++i)
                            acc[i][j] = __builtin_amdgcn_mfma_f32_16x16x32_f16(ah[i], wbh[p][j], acc[i][j], 0, 0, 0);
                    }
                }
            }
        }
    }

    const size_t nb = (size_t)bb * NN + (size_t)(h0 + mg) * 64;
    if (threePass) {
        __bf16* Hi = conv ? Khi : Qhi;
        __bf16* Lo = conv ? Klo : Qlo;
#pragma unroll
        for (int i = 0; i < 4; ++i) {
            const int wx0 = i * 16 + quad * 4;
#pragma unroll
            for (int j = 0; j < 4; ++j) {
                const int co = ng * 64 + j * 16 + l16;
#pragma unroll
                for (int r = 0; r < 4; ++r) {
                    const float v = acc[i][j][r];
                    const size_t idx = (nb + wx0 + r) * CCH + co;
                    const __bf16 hq = (__bf16)v;
                    Hi[idx] = hq;
                    Lo[idx] = (__bf16)(v - (float)hq);
                }
            }
        }
    } else {
#pragma unroll
        for (int i = 0; i < 4; ++i) {
            const int wx0 = i * 16 + quad * 4;
#pragma unroll
            for (int j = 0; j < 4; ++j) {
                const int co = ng * 64 + j * 16 + l16;
#pragma unroll
                for (int r = 0; r < 4; ++r)
                    Dws[(nb + wx0 + r) * CCH + co] = acc[i][j][r];
            }
        }
    }
}

// ---------------------------------------------------------------------------
// Transpose D (fp32 [b][n][c]) -> Vt (fp16 [b][c][n]).
// ---------------------------------------------------------------------------
__global__ __launch_bounds__(256)
void transpose_v_kernel(const float* __restrict__ D, _Float16* __restrict__ Vt) {
    __shared__ float T[64][65];
    const int n0 = blockIdx.x * 64, c0 = blockIdx.y * 64, bb = blockIdx.z;
    const int t = threadIdx.x;
    const int row = t >> 2, q = (t & 3) * 16;
#pragma unroll
    for (int k = 0; k < 4; ++k) {
        float4 v = *(const float4*)(D + ((size_t)bb * NN + n0 + row) * CCH + c0 + q + k * 4);
        *(float4*)&T[row][q + k * 4] = v;
    }
    __syncthreads();
    f16x8 o0, o1;
#pragma unroll
    for (int j = 0; j < 8; ++j) o0[j] = (_Float16)T[q + j][row];
#pragma unroll
    for (int j = 0; j < 8; ++j) o1[j] = (_Float16)T[q + 8 + j][row];
    _Float16* dst = Vt + ((size_t)bb * CCH + c0 + row) * NN + n0 + q;
    *(f16x8*)dst = o0;
    *(f16x8*)(dst + 8) = o1;
}

// ---------------------------------------------------------------------------
// MFMA flash attention v9: v7 geometry (512 thr / 8 waves / 128 q, grid 256,
// channel-ownership PV, V direct from L2) with barriers cut 6 -> 4 per tile:
//  - THREE K-chunk buffers (3 x 32KB).  Tile entry: c0,c1 already resident
//    (staged during previous tile's PV -- T14 issue-early/write-late, HBM/L2
//    latency hidden under 64 PV MFMAs).
//  - S-phase: schunk(c0);schunk(c1); B1; kwrite(c3); schunk(c2); B2;
//    schunk(c3) -- 2 barriers, waves drift across 2-chunk spans so the
//    LDS unit (the saturated pipe) stays fed through softmax skew.
//  - PV: kwrite(c0')/kload(c1')/kwrite(c1') sandwiched between qt-halves.
//  - Buffer roles rotate with period 3 (runtime LDS bases, no reg arrays).
// LDS 134144 B -> 1 block/CU.  batch = blockIdx&7 pins batch -> XCD.
// ---------------------------------------------------------------------------
__global__ __launch_bounds__(512, 2)
void attn_mfma_kernel(const __bf16* __restrict__ Qhi, const __bf16* __restrict__ Qlo,
                      const __bf16* __restrict__ Khi, const __bf16* __restrict__ Klo,
                      const _Float16* __restrict__ Vt, const float* __restrict__ alpha_p,
                      float* __restrict__ out) {
    const int bb = blockIdx.x & 7;     // batch -> XCD
    const int qb = blockIdx.x >> 3;    // 0..31
    const int n0 = qb * 128;
    const int tid  = threadIdx.x;
    const int wave = tid >> 6;         // 0..7
    const int lane = tid & 63;
    const int quad = lane >> 4;
    const int l16  = lane & 15;
    const int xq   = l16 & 7;

    extern __shared__ __align__(16) unsigned char smem[];
    // 3 K chunk buffers at smem + r*32768 (hi 16KB, lo 16KB each)
    _Float16* PwA  = (_Float16*)(smem + 98304);   // 8 waves x [16][136] fp16
    float*    Ssc  = (float*)(smem + 133120);     // per-q rescale factor [128]
    float*    Linv = (float*)(smem + 133632);     // per-q alpha/l at end [128]
    _Float16* Pw   = PwA + wave * (16 * 136);

    // Q resident in registers as B-frags: this wave's 16 q-rows
    bf16x8 qh[8], ql[8];
    {
        const size_t base = ((size_t)bb * NN + n0 + wave * 16 + l16) * CCH + quad * 8;
#pragma unroll
        for (int ks = 0; ks < 8; ++ks) {
            qh[ks] = *(const bf16x8*)(Qhi + base + ks * 32);
            ql[ks] = *(const bf16x8*)(Qlo + base + ks * 32);
        }
    }

    // O^T accumulators, channel-ownership: c = wave*32 + cf*16 + quad*4 + r
    f32x4 Oacc[2][8];
#pragma unroll
    for (int cf = 0; cf < 2; ++cf)
#pragma unroll
        for (int qt = 0; qt < 8; ++qt) Oacc[cf][qt] = (f32x4){0.f, 0.f, 0.f, 0.f};
    float m_i = -INFINITY, l_i = 0.f;

    // K staging coords: 4 thr/row (128 rows), 2x16B units each per hi/lo
    const int krow = tid >> 2, kq4 = tid & 3;

    bf16x8 kph[2], kpl[2];     // K-chunk prefetch regs

    auto kload = [&](int m0_, int cc_) {
#pragma unroll
        for (int i = 0; i < 2; ++i) {
            const int u = kq4 * 2 + i;
            const size_t g = ((size_t)bb * NN + m0_ + krow) * CCH + cc_ * 64 + u * 8;
            kph[i] = *(const bf16x8*)(Khi + g);
            kpl[i] = *(const bf16x8*)(Klo + g);
        }
    };
    auto kwrite = [&](unsigned char* base) {
        __bf16* H = (__bf16*)base;
        __bf16* L = (__bf16*)(base + 16384);
#pragma unroll
        for (int i = 0; i < 2; ++i) {
            const int u = kq4 * 2 + i;
            const int lo = krow * 64 + ((u ^ (krow & 7)) * 8);
            *(bf16x8*)&H[lo] = kph[i];
            *(bf16x8*)&L[lo] = kpl[i];
        }
    };

    f32x4 Sacc[8];
    auto schunk = [&](int cc, const unsigned char* base) {
        const __bf16* KH = (const __bf16*)base;
        const __bf16* KL = (const __bf16*)(base + 16384);
#pragma unroll
        for (int ks = 0; ks < 2; ++ks) {
            const int kq = cc * 2 + ks;
#pragma unroll
            for (int kvt = 0; kvt < 8; ++kvt) {
                const int off = (kvt * 16 + l16) * 64 + (((ks * 4 + quad) ^ xq) * 8);
                const bf16x8 kh = *(const bf16x8*)&KH[off];
                const bf16x8 kl = *(const bf16x8*)&KL[off];
                Sacc[kvt] = __builtin_amdgcn_mfma_f32_16x16x32_bf16(kh, qh[kq], Sacc[kvt], 0, 0, 0);
                Sacc[kvt] = __builtin_amdgcn_mfma_f32_16x16x32_bf16(kl, qh[kq], Sacc[kvt], 0, 0, 0);
                Sacc[kvt] = __builtin_amdgcn_mfma_f32_16x16x32_bf16(kh, ql[kq], Sacc[kvt], 0, 0, 0);
            }
        }
    };

    // prologue: stage c0 -> buf0, c1 -> buf1
    kload(0, 0);
    kwrite(smem);
    kload(0, 1);
    kwrite(smem + 32768);
    __syncthreads();

    int rot = 0;   // P0 = buf[rot] (c0), P1 = buf[rot+1] (c1), F = buf[rot+2]

    for (int t = 0; t < 32; ++t) {
        const int m0 = t * 128;
        const int m0n = (t == 31) ? 0 : m0 + 128;
        unsigned char* P0 = smem + rot * 32768;
        unsigned char* P1 = smem + ((rot + 1) % 3) * 32768;
        unsigned char* F  = smem + ((rot + 2) % 3) * 32768;

#pragma unroll
        for (int kvt = 0; kvt < 8; ++kvt) Sacc[kvt] = (f32x4){0.f, 0.f, 0.f, 0.f};

        // ---- S-phase: 2 barriers, 2-chunk sync-free spans ----
        kload(m0, 2);
        schunk(0, P0);
        kwrite(F);                   // c2 -> F (no readers)
        kload(m0, 3);
        schunk(1, P1);
        __syncthreads();             // B1: F(c2) visible; P0,P1 reads done
        kwrite(P0);                  // c3 -> P0
        schunk(2, F);
        __syncthreads();             // B2: P0(c3) visible
        schunk(3, P0);

        // ---- V fragments direct from global (L2-resident tile) ----
        f16x8 vf[2][4];
#pragma unroll
        for (int cf = 0; cf < 2; ++cf)
#pragma unroll
            for (int kvf = 0; kvf < 4; ++kvf)
                vf[cf][kvf] = *(const f16x8*)(Vt +
                    ((size_t)bb * CCH + wave * 32 + cf * 16 + l16) * NN +
                    m0 + kvf * 32 + quad * 8);

        // ---- online softmax over 128 kv (this wave's 16 q-rows) ----
        float mx = -INFINITY;
#pragma unroll
        for (int kvt = 0; kvt < 8; ++kvt)
#pragma unroll
            for (int r = 0; r < 4; ++r) mx = fmaxf(mx, Sacc[kvt][r]);
        mx = fmaxf(mx, __shfl_xor(mx, 16, 64));
        mx = fmaxf(mx, __shfl_xor(mx, 32, 64));
        const float mnew = fmaxf(m_i, mx);
        float rs = 0.f;
#pragma unroll
        for (int kvt = 0; kvt < 8; ++kvt) {
            f16x4 pw;
#pragma unroll
            for (int r = 0; r < 4; ++r) {
                const float p = __expf(Sacc[kvt][r] - mnew);
                rs += p;
                pw[r] = (_Float16)p;
            }
            *(f16x4*)&Pw[l16 * 136 + kvt * 16 + quad * 4] = pw;
        }
        rs += __shfl_xor(rs, 16, 64);
        rs += __shfl_xor(rs, 32, 64);
        const float scale = __expf(m_i - mnew);    // 0 on first tile
        if (quad == 0) Ssc[wave * 16 + l16] = scale;
        l_i = l_i * scale + rs;
        m_i = mnew;
        __syncthreads();             // B3: Pw + Ssc visible; P0(c3) reads done

        // ---- rescale O by per-q factors (broadcast reads) ----
        float sc[8];
#pragma unroll
        for (int qt = 0; qt < 8; ++qt) sc[qt] = Ssc[qt * 16 + l16];
#pragma unroll
        for (int cf = 0; cf < 2; ++cf)
#pragma unroll
            for (int qt = 0; qt < 8; ++qt) {
                Oacc[cf][qt][0] *= sc[qt];
                Oacc[cf][qt][1] *= sc[qt];
                Oacc[cf][qt][2] *= sc[qt];
                Oacc[cf][qt][3] *= sc[qt];
            }

        // ---- PV with next-tile c0/c1 staging sandwiched ----
        kload(m0n, 0);
#pragma unroll
        for (int qt = 0; qt < 4; ++qt) {
            const _Float16* Pq = PwA + qt * (16 * 136);
            f16x8 pf[4];
#pragma unroll
            for (int kvf = 0; kvf < 4; ++kvf)
                pf[kvf] = *(const f16x8*)&Pq[l16 * 136 + kvf * 32 + quad * 8];
#pragma unroll
            for (int cf = 0; cf < 2; ++cf)
#pragma unroll
                for (int kvf = 0; kvf < 4; ++kvf)
                    Oacc[cf][qt] = __builtin_amdgcn_mfma_f32_16x16x32_f16(vf[cf][kvf], pf[kvf], Oacc[cf][qt], 0, 0, 0);
        }
        kwrite(P1);                  // c0' -> P1 (free since B1)
        kload(m0n, 1);
#pragma unroll
        for (int qt = 4; qt < 8; ++qt) {
            const _Float16* Pq = PwA + qt * (16 * 136);
            f16x8 pf[4];
#pragma unroll
            for (int kvf = 0; kvf < 4; ++kvf)
                pf[kvf] = *(const f16x8*)&Pq[l16 * 136 + kvf * 32 + quad * 8];
#pragma unroll
            for (int cf = 0; cf < 2; ++cf)
#pragma unroll
                for (int kvf = 0; kvf < 4; ++kvf)
                    Oacc[cf][qt] = __builtin_amdgcn_mfma_f32_16x16x32_f16(vf[cf][kvf], pf[kvf], Oacc[cf][qt], 0, 0, 0);
        }
        kwrite(F);                   // c1' -> F (reads done before B2)
        __syncthreads();             // B4: P1,F visible; Pw reads done

        rot = (rot + 1) == 3 ? 0 : rot + 1;   // next: c0 in old-P1, c1 in old-F
    }

    // ---- epilogue: per-q 1/l broadcast, *alpha, write out[b][c][n] ----
    const float alpha = *alpha_p;
    if (quad == 0) Linv[wave * 16 + l16] = alpha / l_i;
    __syncthreads();
#pragma unroll
    for (int qt = 0; qt < 8; ++qt) {
        const float inv = Linv[qt * 16 + l16];
#pragma unroll
        for (int cf = 0; cf < 2; ++cf)
#pragma unroll
            for (int r = 0; r < 4; ++r) {
                const int c = wave * 32 + cf * 16 + quad * 4 + r;
                out[((size_t)bb * CCH + c) * NN + n0 + qt * 16 + l16] = Oacc[cf][qt][r] * inv;
            }
    }
}

// ---------------------------------------------------------------------------
extern "C" void kernel_launch(void* const* d_in, const int* in_sizes, int n_in,
                              void* d_out, int out_size, void* d_ws, size_t ws_size,
                              hipStream_t stream) {
    const float* X  = (const float*)d_in[0];
    const float* w1 = (const float*)d_in[1];
    const float* b1 = (const float*)d_in[2];
    const float* w2 = (const float*)d_in[3];
    const float* b2 = (const float*)d_in[4];
    const float* w3 = (const float*)d_in[5];
    const float* b3 = (const float*)d_in[6];
    const float* alpha = (const float*)d_in[7];
    float* out = (float*)d_out;

    float*    Dws = (float*)d_ws;
    __bf16*   Qhi = (__bf16*)(Dws + (size_t)BNC);
    __bf16*   Qlo = Qhi + (size_t)BNC;
    __bf16*   Khi = Qlo + (size_t)BNC;
    __bf16*   Klo = Khi + (size_t)BNC;
    _Float16* Vt  = (_Float16*)(Klo + (size_t)BNC);
    _Float16* Xhi = Vt + (size_t)BNC;
    _Float16* Xlo = Xhi + (size_t)BNC;
    _Float16* Whi = Xlo + (size_t)BNC;
    _Float16* Wlo = Whi + (size_t)WELEMS;

    wtrans_kernel<<<dim3(WELEMS / 256), 256, 0, stream>>>(w1, w2, w3, Whi, Wlo);

    xsplit_kernel<<<dim3(HH, CCH / 64, BATCH), 256, 0, stream>>>(X, Xhi, Xlo);

    conv_mfma_kernel<<<dim3(HH / 2, BATCH, 3), 512, 0, stream>>>(
        Xhi, Xlo, Whi, Wlo, b1, b2, b3, Qhi, Qlo, Khi, Klo, Dws);

    transpose_v_kernel<<<dim3(NN / 64, CCH / 64, BATCH), 256, 0, stream>>>(Dws, Vt);

    // dynamic LDS: K 3x32KB + P 34KB + Ssc/Linv 1KB = 134144 B
    attn_mfma_kernel<<<dim3(256), 512, 134144, stream>>>(
        Qhi, Qlo, Khi, Klo, Vt, alpha, out);
}